// Round 13
// baseline (301.339 us; speedup 1.0000x reference)
//
#include <hip/hip_runtime.h>
#include <stdint.h>

// CrossAttn: B=2, Nr=Np=8192, C=256, K=8. ALL I/O float32.
// R23: REVERT to R21 (passing, 292.3us) after R22's cross-wave-staging
// rewrite failed (absmax 0.254, bug not localizable; R19 vs R21 showed
// occupancy isn't knn's binding constraint anyway). One safe addition:
// k_zero's 32MB serial tail split by region liveness:
//  Z_early (dead-forever: [8.25M,8.75M)+[9M+2K,16M)+[36M,48M)) zeroed by 960
//    extra blocks on the k_prep launch (disjoint from ref4 prep writes);
//  Z_mid (ref4+part, dead after attn) zeroed by bm==256 blocks in k_gemm
//    (disjoint from g/Aw/bbig/pred writes);
//  Z_final (g+Aw+bbig regions, dead after gemm) = residual k_zero, 8.65MB.
// Union == old zero region exactly (20445184+4456448+8652800 = 33554432B).
// Everything else byte-identical to R21.
// Scratch: NO d_ws. All inside d_out dead ref-half regions:
//   g 8MB [0,8M); ref4 [8M,8.25M); Aw [8.75M,9M); bbig [9M,+2K);
//   part u16 4MB [32M,36M).
// k_gemm writes pred halves [16M,32M)+[48M,64M).

#define NRr 8192
#define NPp 8192
#define NC  256
#define NK  8
#define NCH   16     // ref chunks
#define CHUNK 512    // refs per chunk

typedef short bf16x8 __attribute__((ext_vector_type(8)));
typedef float f32x4  __attribute__((ext_vector_type(4)));

__device__ __forceinline__ uint16_t f2bf(float f) {
  uint32_t u = __float_as_uint(f);
  return (uint16_t)((u + 0x7fffu + ((u >> 16) & 1u)) >> 16);
}

// Exact np-f32 d2: rounded products, sequential adds, (sp+sr) - (dot+dot).
// Used by k_knn and the fused merge so recomputation is bitwise identical.
__device__ __forceinline__ float d2f(float px, float py, float pz, float sp, float4 r) {
  float m0 = __fmul_rn(px, r.x), m1 = __fmul_rn(py, r.y), m2 = __fmul_rn(pz, r.z);
  float dot = __fadd_rn(__fadd_rn(m0, m1), m2);
  return __fsub_rn(__fadd_rn(sp, r.w), __fadd_rn(dot, dot));
}

// monotone float->u32 key: total order of floats == unsigned order of keys
__device__ __forceinline__ uint32_t fkey(float f) {
  uint32_t b = __float_as_uint(f);
  return (b & 0x80000000u) ? ~b : (b | 0x80000000u);
}

// ---- prep (blocks 0..255) + Z_early zero (blocks 256..1215) ---------------
// Z_early spans (f4 units): [540672,+32768) [589952,+458624) [2359296,+786432)
// = dead-forever bytes [8650752,9175040)+[9439232,16777216)+[37748736,50331648)
__global__ __launch_bounds__(64) void k_prep(const float* __restrict__ xyz_ref,
                                             float4* __restrict__ ref4,
                                             float4* __restrict__ ob4) {
  if (blockIdx.x >= 256) {
    int z = (blockIdx.x - 256) * 64 + threadIdx.x;   // 0..61439
    float4 zf = make_float4(0.f, 0.f, 0.f, 0.f);
    for (int i = z; i < 1277824; i += 61440) {
      size_t f;
      if (i < 32768)       f = 540672u + i;
      else if (i < 491392) f = 589952u + (i - 32768);
      else                 f = 2359296u + (i - 491392);
      ob4[f] = zf;
    }
    return;
  }
  int i = blockIdx.x * 64 + threadIdx.x;       // 0 .. 2*NR-1 (256 blocks x 64)
  if (i >= 2 * NRr) return;
  float x = xyz_ref[i*3+0];
  float y = xyz_ref[i*3+1];
  float z = xyz_ref[i*3+2];
  float n = __fadd_rn(__fadd_rn(__fmul_rn(x,x), __fmul_rn(y,y)), __fmul_rn(z,z));
  ref4[i] = make_float4(x, y, z, n);
}

// sorted-8 insert, strict < on d2 (scan order ascending idx => lex-stable)
__device__ __forceinline__ void insert8(float d2, int j, float (&dist)[8], int (&id)[8]) {
  if (d2 < dist[7]) {
    #pragma unroll
    for (int k = 7; k >= 1; --k) {
      bool sh = d2 < dist[k-1];
      bool pl = d2 < dist[k];
      float nd = sh ? dist[k-1] : (pl ? d2 : dist[k]);
      int   ni = sh ? id[k-1]   : (pl ? j  : id[k]);
      dist[k] = nd; id[k] = ni;
    }
    if (d2 < dist[0]) { dist[0] = d2; id[0] = j; }
  }
}

// ---- FUSED: blocks 0..63 = combine (Wout@Wo@Wv fold); 64..1087 = KNN -------
// KNN: 4 independent single-wave bodies per 256-thr block; wave-task =
// (blockIdx-64)*4 + wave; ch = task & 15; point-group = task >> 4. Each wave
// stages its OWN LDS segment; no barrier, no cross-wave coupling.
// Combine: byte-identical to the old k_combine (e0 = blockIdx*8).
// LDS union: knn uses [0,32K) as float4 sref[4][512]; combine uses [0,8K) as
// M8[8][256] + [8K,9K) as red[256]. Paths never coexist in one block.
__global__ __launch_bounds__(256, 5) void k_knn(const float* __restrict__ xyz_pred,
                                                const float4* __restrict__ ref4,
                                                uint16_t* __restrict__ part,
                                                const float* __restrict__ Wv,
                                                const float* __restrict__ bv,
                                                const float* __restrict__ Wo,
                                                const float* __restrict__ bo,
                                                const float* __restrict__ Wout,
                                                uint16_t* __restrict__ Aw,
                                                float* __restrict__ bbig) {
  __shared__ __align__(16) char smem[32768];

  if (blockIdx.x < 64) {
    // ================= combine path (verbatim k_combine) ===================
    float (*M8)[256] = (float (*)[256])smem;         // 8 KB
    float* red = (float*)(smem + 8192);              // 1 KB
    int e0 = blockIdx.x * 8;   // 0..511 in groups of 8
    int t  = threadIdx.x;      // 0..255

    float acc8[8];
    #pragma unroll
    for (int e = 0; e < 8; ++e) acc8[e] = 0.f;
    for (int d = 0; d < 256; ++d) {
      float wo = Wo[(size_t)d*256 + t];
      #pragma unroll
      for (int e = 0; e < 8; ++e)
        acc8[e] = fmaf(Wout[(size_t)(e0+e)*256 + d], wo, acc8[e]);
    }
    #pragma unroll
    for (int e = 0; e < 8; ++e) M8[e][t] = acc8[e];
    __syncthreads();

    float a8[8];
    #pragma unroll
    for (int e = 0; e < 8; ++e) a8[e] = 0.f;
    for (int c = 0; c < 256; ++c) {
      float wv = Wv[(size_t)c*256 + t];
      #pragma unroll
      for (int e = 0; e < 8; ++e)
        a8[e] = fmaf(M8[e][c], wv, a8[e]);
    }
    #pragma unroll
    for (int e = 0; e < 8; ++e) Aw[(size_t)(e0+e)*256 + t] = f2bf(a8[e]);

    for (int e = 0; e < 8; ++e) {
      red[t] = fmaf(M8[e][t], bv[t], Wout[(size_t)(e0+e)*256 + t] * bo[t]);
      __syncthreads();
      for (int s2 = 128; s2 > 0; s2 >>= 1) {
        if (t < s2) red[t] += red[t + s2];
        __syncthreads();
      }
      if (t == 0) bbig[e0+e] = red[0];
      __syncthreads();
    }
    return;
  }

  // ============================ knn path ===================================
  float4* sref = (float4*)smem;                      // 32 KB
  int wave = threadIdx.x >> 6;
  int lane = threadIdx.x & 63;
  int task = (blockIdx.x - 64) * 4 + wave;     // 0..4095
  int ch   = task & (NCH - 1);                 // 0..15
  int P    = (task >> 4) * 64 + lane;          // global point 0..16383
  int b    = P >> 13;

  float px = xyz_pred[P*3+0];
  float py = xyz_pred[P*3+1];
  float pz = xyz_pred[P*3+2];
  float sp = __fadd_rn(__fadd_rn(__fmul_rn(px,px), __fmul_rn(py,py)), __fmul_rn(pz,pz));

  const float4* refbase = ref4 + (size_t)b * NRr;
  int rbase = ch * CHUNK;
  float4* srefw = sref + wave * CHUNK;
  for (int j = lane; j < CHUNK; j += 64) srefw[j] = refbase[rbase + j];
  // no __syncthreads: in-wave ds_write -> ds_read ordering via lgkmcnt

  // dual 4-chains: a = top-4 of evens, g = top-4 of odds (ascending order)
  float a0 = 3.4e38f, a1 = 3.4e38f, a2 = 3.4e38f, a3 = 3.4e38f;
  float g0 = 3.4e38f, g1 = 3.4e38f, g2 = 3.4e38f, g3 = 3.4e38f;
  float dist[8]; int id[8];
  #pragma unroll
  for (int k = 0; k < 8; ++k) { dist[k] = 3.4e38f; id[k] = 0; }

  for (int s = 0; s < CHUNK / 32; ++s) {       // 16 segments x 32 candidates
    uint32_t mm = 0;
    int base = s * 32;
    #pragma unroll 2
    for (int jj = 0; jj < 32; jj += 2) {
      float d0 = d2f(px, py, pz, sp, srefw[base + jj]);
      float d1 = d2f(px, py, pz, sp, srefw[base + jj + 1]);
      // chain A <- even candidate; med3(x,lo,hi) == sorted-insert shift
      a3 = __builtin_amdgcn_fmed3f(d0, a2, a3);
      a2 = __builtin_amdgcn_fmed3f(d0, a1, a2);
      a1 = __builtin_amdgcn_fmed3f(d0, a0, a1);
      a0 = fminf(d0, a0);
      // chain G <- odd candidate
      g3 = __builtin_amdgcn_fmed3f(d1, g2, g3);
      g2 = __builtin_amdgcn_fmed3f(d1, g1, g2);
      g1 = __builtin_amdgcn_fmed3f(d1, g0, g1);
      g0 = fminf(d1, g0);
      float tau = fmaxf(a3, g3);               // >= running 8th >= final T8
      mm |= (uint32_t)(d0 <= tau) << jj;
      mm |= (uint32_t)(d1 <= tau) << (jj + 1);
    }
    // finalize this segment's survivors (ascending j, strict <)
    while (mm) {
      int bit = __builtin_ctz(mm); mm &= mm - 1;
      int j = base + bit;
      float dd = d2f(px, py, pz, sp, srefw[j]);
      insert8(dd, j, dist, id);
    }
  }

  uint16_t* pp = part + ((size_t)P * NCH + ch) * 8;
  #pragma unroll
  for (int k = 0; k < 8; ++k)
    pp[k] = (uint16_t)((rbase + id[k]) & (NRr - 1));
}

// ------- attention + fused merge: one wave per pred point -------------------
// Merge: 128 part candidates = 64 u32 (1/lane, coalesced). Each lane: exact
// d2f of its 2 cands (parallel gathers), key = fkey(d2)<<32 | j (monotone,
// lex (d2,j)). 8 rounds of butterfly u64-min + winner masking == insert_lex
// lex top-8 exactly (all j distinct: disjoint chunk ranges).
__global__ __launch_bounds__(256) void k_attn(const float* __restrict__ feat_q,
    const float* __restrict__ feat_k, const float* __restrict__ feat_v,
    const uint16_t* __restrict__ part, const float* __restrict__ xyz_pred,
    const float4* __restrict__ ref4, uint16_t* __restrict__ g) {
  int wave = threadIdx.x >> 6;
  int lane = threadIdx.x & 63;
  int P = blockIdx.x * 4 + wave;     // 0..16383
  int b = P >> 13;

  // ---- fused merge ----
  float px = xyz_pred[P*3+0];
  float py = xyz_pred[P*3+1];
  float pz = xyz_pred[P*3+2];
  float sp = __fadd_rn(__fadd_rn(__fmul_rn(px,px), __fmul_rn(py,py)), __fmul_rn(pz,pz));
  const float4* refbase = ref4 + (size_t)b * NRr;

  const uint32_t* pw = (const uint32_t*)(part + (size_t)P * (NCH * 8));
  uint32_t two = pw[lane];                 // cands 2*lane (lo u16), 2*lane+1 (hi)
  int j0 = two & (NRr - 1);
  int j1 = (two >> 16) & (NRr - 1);
  float d0 = d2f(px, py, pz, sp, refbase[j0]);
  float d1 = d2f(px, py, pz, sp, refbase[j1]);
  uint64_t k0 = ((uint64_t)fkey(d0) << 32) | (uint32_t)j0;
  uint64_t k1 = ((uint64_t)fkey(d1) << 32) | (uint32_t)j1;

  int nb[8];
  #pragma unroll
  for (int r = 0; r < 8; ++r) {
    uint64_t m = (k0 < k1) ? k0 : k1;
    #pragma unroll
    for (int s = 1; s < 64; s <<= 1) {
      uint64_t o = __shfl_xor(m, s, 64);
      m = (o < m) ? o : m;
    }
    nb[r] = (int)(uint32_t)(m & 0xFFFFFFFFu) & (NRr - 1);
    if (k0 == m) k0 = ~0ULL;
    if (k1 == m) k1 = ~0ULL;
  }

  // ---- attention (unchanged) ----
  float4 qv = *(const float4*)(feat_q + (size_t)P*NC + lane*4);
  const float* kb = feat_k + (size_t)b * NRr * NC;
  const float* vb = feat_v + (size_t)b * NRr * NC;

  float s[8];
  #pragma unroll
  for (int k = 0; k < 8; ++k) {
    float4 kv = *(const float4*)(kb + (size_t)nb[k]*NC + lane*4);
    float p = qv.x * kv.x;
    p = fmaf(qv.y, kv.y, p);
    p = fmaf(qv.z, kv.z, p);
    p = fmaf(qv.w, kv.w, p);
    s[k] = p;
  }
  #pragma unroll
  for (int k = 0; k < 8; ++k) {
    float v = s[k];
    #pragma unroll
    for (int m = 1; m < 64; m <<= 1) v += __shfl_xor(v, m, 64);
    s[k] = v * 0.0625f;   // / sqrt(256), exact
  }
  float mx = s[0];
  #pragma unroll
  for (int k = 1; k < 8; ++k) mx = fmaxf(mx, s[k]);
  float e[8], sum = 0.f;
  #pragma unroll
  for (int k = 0; k < 8; ++k) { e[k] = expf(s[k] - mx); sum += e[k]; }
  float inv = 1.0f / sum;

  float g0 = 0.f, g1 = 0.f, g2 = 0.f, g3 = 0.f;
  #pragma unroll
  for (int k = 0; k < 8; ++k) {
    float4 vv = *(const float4*)(vb + (size_t)nb[k]*NC + lane*4);
    float w = e[k] * inv;
    g0 = fmaf(w, vv.x, g0);
    g1 = fmaf(w, vv.y, g1);
    g2 = fmaf(w, vv.z, g2);
    g3 = fmaf(w, vv.w, g3);
  }
  uint32_t p0 = ((uint32_t)f2bf(g1) << 16) | f2bf(g0);
  uint32_t p1 = ((uint32_t)f2bf(g3) << 16) | f2bf(g2);
  *(uint2*)(g + (size_t)P*NC + lane*4) = make_uint2(p0, p1);
}

// ---- residual zero (runs LAST): g [0,8M) + Aw/bbig [9175040,9439232) ------
// f4 spans: [0,524288) and [573440,+16512); total 540800 f4.
__global__ void k_zero(float4* __restrict__ o) {
  int z = blockIdx.x * 256 + threadIdx.x;   // 0..524287 (2048 blocks)
  float4 zf = make_float4(0.f, 0.f, 0.f, 0.f);
  for (int i = z; i < 540800; i += 524288) {
    size_t f = (i < 524288) ? (size_t)i : (size_t)(573440 + (i - 524288));
    o[f] = zf;
  }
}

// ---- final GEMM (bm<256) + Z_mid zero (bm==256): ---------------------------
// Z_mid: ref4 [8388608,8650752) + part [33554432,37748736) -- both dead after
// attn; disjoint from g/Aw/bbig reads and pred writes. f4 spans:
// [524288,+16384) and [2097152,+262144); total 278528 f4.
__global__ __launch_bounds__(256) void k_gemm(const uint16_t* __restrict__ g,
    const uint16_t* __restrict__ Aw, const float* __restrict__ bbig,
    float* __restrict__ outp) {
  // LDS stride 136 (272B): 16B-aligned rows, 4-bank shift/row => conflict-free
  __shared__ __align__(16) uint16_t sA[64 * 136];
  __shared__ __align__(16) uint16_t sB[64 * 136];
  int bm = blockIdx.x;   // 0..255 (M tiles of 64); 256 = zero blocks
  int bn = blockIdx.y;   // 0..7   (N tiles of 64)
  if (bm == 256) {
    int z = bn * 256 + threadIdx.x;          // 0..2047
    float4 zf = make_float4(0.f, 0.f, 0.f, 0.f);
    float4* o4 = (float4*)outp;
    for (int i = z; i < 278528; i += 2048) {
      size_t f = (i < 16384) ? (size_t)(524288 + i)
                             : (size_t)(2097152 + (i - 16384));
      o4[f] = zf;
    }
    return;
  }
  int t = threadIdx.x;
  int lane = t & 63, wave = t >> 6;
  int wm = (wave >> 1) * 32, wn = (wave & 1) * 32;
  int q = lane >> 4, rr = lane & 15;
  f32x4 zero = {0.f, 0.f, 0.f, 0.f};
  f32x4 acc[2][2] = {{zero, zero}, {zero, zero}};

  for (int ph = 0; ph < 2; ++ph) {      // K = 256 in two 128 phases
    #pragma unroll
    for (int i = 0; i < 4; ++i) {
      int cc  = t + i * 256;            // 0..1023 chunks of 8 bf16
      int row = cc >> 4;                // 16 chunks per row
      int col = (cc & 15) << 3;
      uint4 da = *(const uint4*)(g  + ((size_t)(bm*64 + row))*NC + ph*128 + col);
      *(uint4*)(&sA[row*136 + col]) = da;
      uint4 db = *(const uint4*)(Aw + ((size_t)(bn*64 + row))*NC + ph*128 + col);
      *(uint4*)(&sB[row*136 + col]) = db;
    }
    __syncthreads();
    #pragma unroll
    for (int kk = 0; kk < 4; ++kk) {
      int ko = kk*32 + q*8;
      bf16x8 a0 = *(const bf16x8*)(&sA[(wm      + rr)*136 + ko]);
      bf16x8 a1 = *(const bf16x8*)(&sA[(wm + 16 + rr)*136 + ko]);
      bf16x8 b0 = *(const bf16x8*)(&sB[(wn      + rr)*136 + ko]);
      bf16x8 b1 = *(const bf16x8*)(&sB[(wn + 16 + rr)*136 + ko]);
      acc[0][0] = __builtin_amdgcn_mfma_f32_16x16x32_bf16(a0, b0, acc[0][0], 0, 0, 0);
      acc[0][1] = __builtin_amdgcn_mfma_f32_16x16x32_bf16(a0, b1, acc[0][1], 0, 0, 0);
      acc[1][0] = __builtin_amdgcn_mfma_f32_16x16x32_bf16(a1, b0, acc[1][0], 0, 0, 0);
      acc[1][1] = __builtin_amdgcn_mfma_f32_16x16x32_bf16(a1, b1, acc[1][1], 0, 0, 0);
    }
    __syncthreads();
  }
  #pragma unroll
  for (int j = 0; j < 2; ++j) {
    int col = bn*64 + wn + j*16 + rr;
    float bias = bbig[col];
    #pragma unroll
    for (int i = 0; i < 2; ++i) {
      #pragma unroll
      for (int r = 0; r < 4; ++r) {
        int row = bm*64 + wm + i*16 + q*4 + r;   // C/D: col=lane&15, row=(lane>>4)*4+reg
        float v = acc[i][j][r] + bias;
        int bb = row >> 13, p = row & 8191;
        outp[((size_t)(bb*16384 + 8192 + p))*512 + col] = v;
      }
    }
  }
}

extern "C" void kernel_launch(void* const* d_in, const int* in_sizes, int n_in,
                              void* d_out, int out_size, void* d_ws, size_t ws_size,
                              hipStream_t stream) {
  const float* xyz_ref  = (const float*)d_in[0];
  const float* xyz_pred = (const float*)d_in[1];
  const float* feat_k   = (const float*)d_in[2];
  const float* feat_q   = (const float*)d_in[3];
  const float* feat_v   = (const float*)d_in[4];
  const float* Wv       = (const float*)d_in[5];
  const float* bv       = (const float*)d_in[6];
  const float* Wo       = (const float*)d_in[7];
  const float* bo       = (const float*)d_in[8];
  const float* Wout     = (const float*)d_in[9];
  float* outp = (float*)d_out;

  // ALL scratch inside d_out's dead ref-half regions (f32 output, 64MB):
  char* ob = (char*)d_out;
  uint16_t* g    = (uint16_t*)ob;                    // [0, 8M)    bf16 16384x256
  float4*   ref4 = (float4*)(ob + 8388608);          // [8M, 8.25M)
  uint16_t* Aw   = (uint16_t*)(ob + 9175040);        // [8.75M, 9M)
  float*    bbig = (float*)(ob + 9437184);           // [9M, +2K)
  uint16_t* part = (uint16_t*)(ob + 33554432);       // [32M, 36M)  4 MB u16

  k_prep   <<<1216, 64,  0, stream>>>(xyz_ref, ref4, (float4*)outp);
  k_knn    <<<1088, 256, 0, stream>>>(xyz_pred, ref4, part,
                                      Wv, bv, Wo, bo, Wout, Aw, bbig);
  k_attn   <<<4096, 256, 0, stream>>>(feat_q, feat_k, feat_v, part,
                                      xyz_pred, ref4, g);
  k_gemm   <<<dim3(257, 8), 256, 0, stream>>>(g, Aw, bbig, outp);
  k_zero   <<<2048, 256, 0, stream>>>((float4*)outp);
}

// Round 14
// 283.815 us; speedup vs baseline: 1.0617x; 1.0617x over previous
//
#include <hip/hip_runtime.h>
#include <stdint.h>

// CrossAttn: B=2, Nr=Np=8192, C=256, K=8. ALL I/O float32.
// R24: base = R21 (passing, 292.3us; R23's zero-split REVERTED -- it lost
// ~9us: prep inflation + gemm CU theft + less-parallel residual zero).
// One surgical k_knn change: the mask pass uses CHEAP d2 (d2q: mul+2fma+
// add+fma = 5 instrs vs exact d2f's 7) and compares vs tau+SLACK.
// Safety: intermediates <= ~12e3 => ulp ~1e-3 => |d2q-d2f| <= E ~8e-3.
// True top-8 x: cheap(x) <= exact(x)+E <= T8exact+E <= C8cheap+2E <=
// running-tau-cheap+2E; SLACK=0.0625 >= 4x margin => bit always set =>
// superset. Finalize recomputes EXACT d2f + strict-< ascending-j insert8
// => part bit-identical; survivor inflation ~0.3/point (negligible).
// Also jj-loop unroll 2->4 (4 in-flight b128 loads, R14-proven) to cut
// loop/branch overhead. Everything else byte-identical to R21.
// Scratch: NO d_ws. All inside d_out dead ref-half regions:
//   g 8MB [0,8M); ref4 [8M,8.25M); Aw [8.75M,9M); bbig [9M,+2K);
//   part u16 4MB [32M,36M).
// k_gemm writes pred halves [16M,32M)+[48M,64M); k_zero zeroes ref halves LAST.

#define NRr 8192
#define NPp 8192
#define NC  256
#define NK  8
#define NCH   16     // ref chunks
#define CHUNK 512    // refs per chunk

typedef short bf16x8 __attribute__((ext_vector_type(8)));
typedef float f32x4  __attribute__((ext_vector_type(4)));

__device__ __forceinline__ uint16_t f2bf(float f) {
  uint32_t u = __float_as_uint(f);
  return (uint16_t)((u + 0x7fffu + ((u >> 16) & 1u)) >> 16);
}

// Exact np-f32 d2: rounded products, sequential adds, (sp+sr) - (dot+dot).
// Used by k_knn finalize and the fused merge: recomputation bitwise identical.
__device__ __forceinline__ float d2f(float px, float py, float pz, float sp, float4 r) {
  float m0 = __fmul_rn(px, r.x), m1 = __fmul_rn(py, r.y), m2 = __fmul_rn(pz, r.z);
  float dot = __fadd_rn(__fadd_rn(m0, m1), m2);
  return __fsub_rn(__fadd_rn(sp, r.w), __fadd_rn(dot, dot));
}

// cheap d2 for the MASK PASS only (5 instrs); |d2q - d2f| <= ~8e-3 here.
__device__ __forceinline__ float d2q(float px, float py, float pz, float sp, float4 r) {
  float dot = fmaf(px, r.x, fmaf(py, r.y, pz * r.z));
  return fmaf(-2.f, dot, sp + r.w);
}

#define SLACK 0.0625f

// monotone float->u32 key: total order of floats == unsigned order of keys
__device__ __forceinline__ uint32_t fkey(float f) {
  uint32_t b = __float_as_uint(f);
  return (b & 0x80000000u) ? ~b : (b | 0x80000000u);
}

// ---------------- prep: ref coords + |r|^2 (literal np rounding) ------------
__global__ __launch_bounds__(64) void k_prep(const float* __restrict__ xyz_ref,
                                             float4* __restrict__ ref4) {
  int i = blockIdx.x * 64 + threadIdx.x;       // 0 .. 2*NR-1 (256 blocks x 64)
  if (i >= 2 * NRr) return;
  float x = xyz_ref[i*3+0];
  float y = xyz_ref[i*3+1];
  float z = xyz_ref[i*3+2];
  float n = __fadd_rn(__fadd_rn(__fmul_rn(x,x), __fmul_rn(y,y)), __fmul_rn(z,z));
  ref4[i] = make_float4(x, y, z, n);
}

// sorted-8 insert, strict < on d2 (scan order ascending idx => lex-stable)
__device__ __forceinline__ void insert8(float d2, int j, float (&dist)[8], int (&id)[8]) {
  if (d2 < dist[7]) {
    #pragma unroll
    for (int k = 7; k >= 1; --k) {
      bool sh = d2 < dist[k-1];
      bool pl = d2 < dist[k];
      float nd = sh ? dist[k-1] : (pl ? d2 : dist[k]);
      int   ni = sh ? id[k-1]   : (pl ? j  : id[k]);
      dist[k] = nd; id[k] = ni;
    }
    if (d2 < dist[0]) { dist[0] = d2; id[0] = j; }
  }
}

// ---- FUSED: blocks 0..63 = combine (Wout@Wo@Wv fold); 64..1087 = KNN -------
// KNN: 4 independent single-wave bodies per 256-thr block; wave-task =
// (blockIdx-64)*4 + wave; ch = task & 15; point-group = task >> 4. Each wave
// stages its OWN LDS segment; no barrier, no cross-wave coupling.
// Combine: byte-identical to the old k_combine (e0 = blockIdx*8).
// LDS union: knn uses [0,32K) as float4 sref[4][512]; combine uses [0,8K) as
// M8[8][256] + [8K,9K) as red[256]. Paths never coexist in one block.
__global__ __launch_bounds__(256, 5) void k_knn(const float* __restrict__ xyz_pred,
                                                const float4* __restrict__ ref4,
                                                uint16_t* __restrict__ part,
                                                const float* __restrict__ Wv,
                                                const float* __restrict__ bv,
                                                const float* __restrict__ Wo,
                                                const float* __restrict__ bo,
                                                const float* __restrict__ Wout,
                                                uint16_t* __restrict__ Aw,
                                                float* __restrict__ bbig) {
  __shared__ __align__(16) char smem[32768];

  if (blockIdx.x < 64) {
    // ================= combine path (verbatim k_combine) ===================
    float (*M8)[256] = (float (*)[256])smem;         // 8 KB
    float* red = (float*)(smem + 8192);              // 1 KB
    int e0 = blockIdx.x * 8;   // 0..511 in groups of 8
    int t  = threadIdx.x;      // 0..255

    float acc8[8];
    #pragma unroll
    for (int e = 0; e < 8; ++e) acc8[e] = 0.f;
    for (int d = 0; d < 256; ++d) {
      float wo = Wo[(size_t)d*256 + t];
      #pragma unroll
      for (int e = 0; e < 8; ++e)
        acc8[e] = fmaf(Wout[(size_t)(e0+e)*256 + d], wo, acc8[e]);
    }
    #pragma unroll
    for (int e = 0; e < 8; ++e) M8[e][t] = acc8[e];
    __syncthreads();

    float a8[8];
    #pragma unroll
    for (int e = 0; e < 8; ++e) a8[e] = 0.f;
    for (int c = 0; c < 256; ++c) {
      float wv = Wv[(size_t)c*256 + t];
      #pragma unroll
      for (int e = 0; e < 8; ++e)
        a8[e] = fmaf(M8[e][c], wv, a8[e]);
    }
    #pragma unroll
    for (int e = 0; e < 8; ++e) Aw[(size_t)(e0+e)*256 + t] = f2bf(a8[e]);

    for (int e = 0; e < 8; ++e) {
      red[t] = fmaf(M8[e][t], bv[t], Wout[(size_t)(e0+e)*256 + t] * bo[t]);
      __syncthreads();
      for (int s2 = 128; s2 > 0; s2 >>= 1) {
        if (t < s2) red[t] += red[t + s2];
        __syncthreads();
      }
      if (t == 0) bbig[e0+e] = red[0];
      __syncthreads();
    }
    return;
  }

  // ============================ knn path ===================================
  float4* sref = (float4*)smem;                      // 32 KB
  int wave = threadIdx.x >> 6;
  int lane = threadIdx.x & 63;
  int task = (blockIdx.x - 64) * 4 + wave;     // 0..4095
  int ch   = task & (NCH - 1);                 // 0..15
  int P    = (task >> 4) * 64 + lane;          // global point 0..16383
  int b    = P >> 13;

  float px = xyz_pred[P*3+0];
  float py = xyz_pred[P*3+1];
  float pz = xyz_pred[P*3+2];
  float sp = __fadd_rn(__fadd_rn(__fmul_rn(px,px), __fmul_rn(py,py)), __fmul_rn(pz,pz));

  const float4* refbase = ref4 + (size_t)b * NRr;
  int rbase = ch * CHUNK;
  float4* srefw = sref + wave * CHUNK;
  for (int j = lane; j < CHUNK; j += 64) srefw[j] = refbase[rbase + j];
  // no __syncthreads: in-wave ds_write -> ds_read ordering via lgkmcnt

  // dual 4-chains on CHEAP d2: a = top-4 of evens, g = top-4 of odds
  float a0 = 3.4e38f, a1 = 3.4e38f, a2 = 3.4e38f, a3 = 3.4e38f;
  float g0 = 3.4e38f, g1 = 3.4e38f, g2 = 3.4e38f, g3 = 3.4e38f;
  float dist[8]; int id[8];
  #pragma unroll
  for (int k = 0; k < 8; ++k) { dist[k] = 3.4e38f; id[k] = 0; }

  for (int s = 0; s < CHUNK / 32; ++s) {       // 16 segments x 32 candidates
    uint32_t mm = 0;
    int base = s * 32;
    #pragma unroll 4
    for (int jj = 0; jj < 32; jj += 2) {
      float d0 = d2q(px, py, pz, sp, srefw[base + jj]);
      float d1 = d2q(px, py, pz, sp, srefw[base + jj + 1]);
      // chain A <- even candidate; med3(x,lo,hi) == sorted-insert shift
      a3 = __builtin_amdgcn_fmed3f(d0, a2, a3);
      a2 = __builtin_amdgcn_fmed3f(d0, a1, a2);
      a1 = __builtin_amdgcn_fmed3f(d0, a0, a1);
      a0 = fminf(d0, a0);
      // chain G <- odd candidate
      g3 = __builtin_amdgcn_fmed3f(d1, g2, g3);
      g2 = __builtin_amdgcn_fmed3f(d1, g1, g2);
      g1 = __builtin_amdgcn_fmed3f(d1, g0, g1);
      g0 = fminf(d1, g0);
      float tau = fmaxf(a3, g3) + SLACK;       // cheap-tau + 2E-safe slack
      mm |= (uint32_t)(d0 <= tau) << jj;
      mm |= (uint32_t)(d1 <= tau) << (jj + 1);
    }
    // finalize this segment's survivors (EXACT d2f, ascending j, strict <)
    while (mm) {
      int bit = __builtin_ctz(mm); mm &= mm - 1;
      int j = base + bit;
      float dd = d2f(px, py, pz, sp, srefw[j]);
      insert8(dd, j, dist, id);
    }
  }

  uint16_t* pp = part + ((size_t)P * NCH + ch) * 8;
  #pragma unroll
  for (int k = 0; k < 8; ++k)
    pp[k] = (uint16_t)((rbase + id[k]) & (NRr - 1));
}

// ------- attention + fused merge: one wave per pred point -------------------
// Merge: 128 part candidates = 64 u32 (1/lane, coalesced). Each lane: exact
// d2f of its 2 cands (parallel gathers), key = fkey(d2)<<32 | j (monotone,
// lex (d2,j)). 8 rounds of butterfly u64-min + winner masking == insert_lex
// lex top-8 exactly (all j distinct: disjoint chunk ranges).
__global__ __launch_bounds__(256) void k_attn(const float* __restrict__ feat_q,
    const float* __restrict__ feat_k, const float* __restrict__ feat_v,
    const uint16_t* __restrict__ part, const float* __restrict__ xyz_pred,
    const float4* __restrict__ ref4, uint16_t* __restrict__ g) {
  int wave = threadIdx.x >> 6;
  int lane = threadIdx.x & 63;
  int P = blockIdx.x * 4 + wave;     // 0..16383
  int b = P >> 13;

  // ---- fused merge ----
  float px = xyz_pred[P*3+0];
  float py = xyz_pred[P*3+1];
  float pz = xyz_pred[P*3+2];
  float sp = __fadd_rn(__fadd_rn(__fmul_rn(px,px), __fmul_rn(py,py)), __fmul_rn(pz,pz));
  const float4* refbase = ref4 + (size_t)b * NRr;

  const uint32_t* pw = (const uint32_t*)(part + (size_t)P * (NCH * 8));
  uint32_t two = pw[lane];                 // cands 2*lane (lo u16), 2*lane+1 (hi)
  int j0 = two & (NRr - 1);
  int j1 = (two >> 16) & (NRr - 1);
  float d0 = d2f(px, py, pz, sp, refbase[j0]);
  float d1 = d2f(px, py, pz, sp, refbase[j1]);
  uint64_t k0 = ((uint64_t)fkey(d0) << 32) | (uint32_t)j0;
  uint64_t k1 = ((uint64_t)fkey(d1) << 32) | (uint32_t)j1;

  int nb[8];
  #pragma unroll
  for (int r = 0; r < 8; ++r) {
    uint64_t m = (k0 < k1) ? k0 : k1;
    #pragma unroll
    for (int s = 1; s < 64; s <<= 1) {
      uint64_t o = __shfl_xor(m, s, 64);
      m = (o < m) ? o : m;
    }
    nb[r] = (int)(uint32_t)(m & 0xFFFFFFFFu) & (NRr - 1);
    if (k0 == m) k0 = ~0ULL;
    if (k1 == m) k1 = ~0ULL;
  }

  // ---- attention (unchanged) ----
  float4 qv = *(const float4*)(feat_q + (size_t)P*NC + lane*4);
  const float* kb = feat_k + (size_t)b * NRr * NC;
  const float* vb = feat_v + (size_t)b * NRr * NC;

  float s[8];
  #pragma unroll
  for (int k = 0; k < 8; ++k) {
    float4 kv = *(const float4*)(kb + (size_t)nb[k]*NC + lane*4);
    float p = qv.x * kv.x;
    p = fmaf(qv.y, kv.y, p);
    p = fmaf(qv.z, kv.z, p);
    p = fmaf(qv.w, kv.w, p);
    s[k] = p;
  }
  #pragma unroll
  for (int k = 0; k < 8; ++k) {
    float v = s[k];
    #pragma unroll
    for (int m = 1; m < 64; m <<= 1) v += __shfl_xor(v, m, 64);
    s[k] = v * 0.0625f;   // / sqrt(256), exact
  }
  float mx = s[0];
  #pragma unroll
  for (int k = 1; k < 8; ++k) mx = fmaxf(mx, s[k]);
  float e[8], sum = 0.f;
  #pragma unroll
  for (int k = 0; k < 8; ++k) { e[k] = expf(s[k] - mx); sum += e[k]; }
  float inv = 1.0f / sum;

  float g0 = 0.f, g1 = 0.f, g2 = 0.f, g3 = 0.f;
  #pragma unroll
  for (int k = 0; k < 8; ++k) {
    float4 vv = *(const float4*)(vb + (size_t)nb[k]*NC + lane*4);
    float w = e[k] * inv;
    g0 = fmaf(w, vv.x, g0);
    g1 = fmaf(w, vv.y, g1);
    g2 = fmaf(w, vv.z, g2);
    g3 = fmaf(w, vv.w, g3);
  }
  uint32_t p0 = ((uint32_t)f2bf(g1) << 16) | f2bf(g0);
  uint32_t p1 = ((uint32_t)f2bf(g3) << 16) | f2bf(g2);
  *(uint2*)(g + (size_t)P*NC + lane*4) = make_uint2(p0, p1);
}

// ---------------- zero-fill ref halves of output (runs LAST) ----------------
__global__ void k_zero(float4* __restrict__ o) {
  int i = blockIdx.x * 256 + threadIdx.x;  // 0 .. 2097151
  int b = i >> 20;                         // region 0 or 1
  int r = i & 1048575;                     // 1M float4 per 16MB region
  o[(size_t)b * 2097152 + r] = make_float4(0.f, 0.f, 0.f, 0.f);
}

// ---------------- final GEMM: g[16384,256]bf16 @ A^T + bbig -> f32 ----------
__global__ __launch_bounds__(256) void k_gemm(const uint16_t* __restrict__ g,
    const uint16_t* __restrict__ Aw, const float* __restrict__ bbig,
    float* __restrict__ outp) {
  // LDS stride 136 (272B): 16B-aligned rows, 4-bank shift/row => conflict-free
  __shared__ __align__(16) uint16_t sA[64 * 136];
  __shared__ __align__(16) uint16_t sB[64 * 136];
  int t = threadIdx.x;
  int lane = t & 63, wave = t >> 6;
  int wm = (wave >> 1) * 32, wn = (wave & 1) * 32;
  int q = lane >> 4, rr = lane & 15;
  int bm = blockIdx.x;   // 0..255 (M tiles of 64)
  int bn = blockIdx.y;   // 0..7   (N tiles of 64)
  f32x4 zero = {0.f, 0.f, 0.f, 0.f};
  f32x4 acc[2][2] = {{zero, zero}, {zero, zero}};

  for (int ph = 0; ph < 2; ++ph) {      // K = 256 in two 128 phases
    #pragma unroll
    for (int i = 0; i < 4; ++i) {
      int cc  = t + i * 256;            // 0..1023 chunks of 8 bf16
      int row = cc >> 4;                // 16 chunks per row
      int col = (cc & 15) << 3;
      uint4 da = *(const uint4*)(g  + ((size_t)(bm*64 + row))*NC + ph*128 + col);
      *(uint4*)(&sA[row*136 + col]) = da;
      uint4 db = *(const uint4*)(Aw + ((size_t)(bn*64 + row))*NC + ph*128 + col);
      *(uint4*)(&sB[row*136 + col]) = db;
    }
    __syncthreads();
    #pragma unroll
    for (int kk = 0; kk < 4; ++kk) {
      int ko = kk*32 + q*8;
      bf16x8 a0 = *(const bf16x8*)(&sA[(wm      + rr)*136 + ko]);
      bf16x8 a1 = *(const bf16x8*)(&sA[(wm + 16 + rr)*136 + ko]);
      bf16x8 b0 = *(const bf16x8*)(&sB[(wn      + rr)*136 + ko]);
      bf16x8 b1 = *(const bf16x8*)(&sB[(wn + 16 + rr)*136 + ko]);
      acc[0][0] = __builtin_amdgcn_mfma_f32_16x16x32_bf16(a0, b0, acc[0][0], 0, 0, 0);
      acc[0][1] = __builtin_amdgcn_mfma_f32_16x16x32_bf16(a0, b1, acc[0][1], 0, 0, 0);
      acc[1][0] = __builtin_amdgcn_mfma_f32_16x16x32_bf16(a1, b0, acc[1][0], 0, 0, 0);
      acc[1][1] = __builtin_amdgcn_mfma_f32_16x16x32_bf16(a1, b1, acc[1][1], 0, 0, 0);
    }
    __syncthreads();
  }
  #pragma unroll
  for (int j = 0; j < 2; ++j) {
    int col = bn*64 + wn + j*16 + rr;
    float bias = bbig[col];
    #pragma unroll
    for (int i = 0; i < 2; ++i) {
      #pragma unroll
      for (int r = 0; r < 4; ++r) {
        int row = bm*64 + wm + i*16 + q*4 + r;   // C/D: col=lane&15, row=(lane>>4)*4+reg
        float v = acc[i][j][r] + bias;
        int bb = row >> 13, p = row & 8191;
        outp[((size_t)(bb*16384 + 8192 + p))*512 + col] = v;
      }
    }
  }
}

extern "C" void kernel_launch(void* const* d_in, const int* in_sizes, int n_in,
                              void* d_out, int out_size, void* d_ws, size_t ws_size,
                              hipStream_t stream) {
  const float* xyz_ref  = (const float*)d_in[0];
  const float* xyz_pred = (const float*)d_in[1];
  const float* feat_k   = (const float*)d_in[2];
  const float* feat_q   = (const float*)d_in[3];
  const float* feat_v   = (const float*)d_in[4];
  const float* Wv       = (const float*)d_in[5];
  const float* bv       = (const float*)d_in[6];
  const float* Wo       = (const float*)d_in[7];
  const float* bo       = (const float*)d_in[8];
  const float* Wout     = (const float*)d_in[9];
  float* outp = (float*)d_out;

  // ALL scratch inside d_out's dead ref-half regions (f32 output, 64MB):
  char* ob = (char*)d_out;
  uint16_t* g    = (uint16_t*)ob;                    // [0, 8M)    bf16 16384x256
  float4*   ref4 = (float4*)(ob + 8388608);          // [8M, 8.25M)
  uint16_t* Aw   = (uint16_t*)(ob + 9175040);        // [8.75M, 9M)
  float*    bbig = (float*)(ob + 9437184);           // [9M, +2K)
  uint16_t* part = (uint16_t*)(ob + 33554432);       // [32M, 36M)  4 MB u16

  k_prep   <<<256,  64,  0, stream>>>(xyz_ref, ref4);
  k_knn    <<<1088, 256, 0, stream>>>(xyz_pred, ref4, part,
                                      Wv, bv, Wo, bo, Wout, Aw, bbig);
  k_attn   <<<4096, 256, 0, stream>>>(feat_q, feat_k, feat_v, part,
                                      xyz_pred, ref4, g);
  k_gemm   <<<dim3(256, 8), 256, 0, stream>>>(g, Aw, bbig, outp);
  k_zero   <<<8192, 256, 0, stream>>>((float4*)outp);
}